// Round 7
// baseline (88.825 us; speedup 1.0000x reference)
//
#include <hip/hip_runtime.h>

// 4-qubit, 2-layer QML circuit, B=1M samples, one thread/sample.
// ROUND 7: single-variable experiment on the round-6 kernel —
// __launch_bounds__(256, 8) caps VGPRs at 64 to move the kernel from the
// 65-128 VGPR occupancy bucket (4 waves/SIMD) into the <=64 bucket
// (8 waves/SIMD). gfx950 occupancy quantizes at VGPR=64/128/256; peak live
// state here is ~56-60 regs (st=32, c/s=8, butterfly temps ~12), so the cap
// should be reachable by scheduler throttling rather than spilling.
// Evidence this is the lever: instruction cuts (R3/R5, -25%) did nothing,
// while every occupancy-REDUCING change (R2 2-sample, R4 4-sample) hurt
// monotonically -> kernel is latency-bound, not issue-bound.
//
// Everything else is byte-identical to round 6 (86-88 us, tied best):
// float2 ext-vector amplitudes, splat*vec FMA chains (v_pk_fma_f32 with
// op_sel/neg), RZ-drop (layer-2 RZ dead under CNOT perm + |.|^2),
// layer-2 U = RY*RX SU(2) butterflies on all 4 qubits, p[16] + tree.
//
// Flat amp index n = q0*8 + q1*4 + q2*2 + q3 (qubit 0 = bit 3).
// Weight-only constants in d_ws (40 floats) via tiny precompute kernel ->
// uniform s_loads -> SGPRs.

typedef float v2f __attribute__((ext_vector_type(2)));

__device__ __forceinline__ v2f splat2(float a) { v2f r; r.x = a; r.y = a; return r; }

__device__ __forceinline__ v2f pfma(float a, v2f b, v2f c) {
    return __builtin_elementwise_fma(splat2(a), b, c);
}

// swneg(a) = {-a.y, a.x}   (multiply-by-i pattern; folds to op_sel+neg)
__device__ __forceinline__ v2f swneg(v2f a) { return __builtin_shufflevector(a, -a, 3, 0); }
// swconj(a) = {a.y, -a.x}
__device__ __forceinline__ v2f swconj(v2f a) { return __builtin_shufflevector(a, -a, 1, 2); }

// complex multiply: a*b = splat(a.re)*b + splat(a.im)*{-b.im, b.re}
__device__ __forceinline__ v2f cmul(v2f a, v2f b) {
    return pfma(a.x, b, splat2(a.y) * swneg(b));
}

// ---- precompute weight-only gate constants (40 floats) ----
// g[0..31]:  l=0 qubit q: g[q*8 + 0..7] = Pr,Pi,Qr,Qi,Rr,Ri,Sr,Si
// g[32..39]: l=1 qubit q: g[32 + q*2 + {0,1}] = cos(wy/2), sin(wy/2)
__global__ void precompute_gates(const float* __restrict__ w, float* __restrict__ g) {
    int t = threadIdx.x;  // 0..7 -> l*4 + q
    if (t >= 8) return;
    int l = t >> 2, q = t & 3;
    if (l == 0) {
        float thy = w[q * 2 + 0];
        float thz = w[q * 2 + 1];
        float cy = cosf(0.5f * thy), sy = sinf(0.5f * thy);
        float cz = cosf(0.5f * thz), sz = sinf(0.5f * thz);
        float* o = g + q * 8;
        // v0 = c*P + s*Q ; v1 = c*R + s*S  (RZ*RY*RX|0>)
        o[0] = cz * cy;  o[1] = -sz * cy;
        o[2] = sz * sy;  o[3] =  cz * sy;
        o[4] = cz * sy;  o[5] =  sz * sy;
        o[6] = sz * cy;  o[7] = -cz * cy;
    } else {
        float thy = w[8 + q * 2 + 0];  // layer-2 RZ params are dead
        g[32 + q * 2 + 0] = cosf(0.5f * thy);
        g[32 + q * 2 + 1] = sinf(0.5f * thy);
    }
}

__device__ __forceinline__ void cnot_chain(v2f st[16]) {
    // CNOT(0,1): q0=1 -> flip q1: swap n=8..11 <-> 12..15
    #pragma unroll
    for (int j = 0; j < 4; j++) { v2f t = st[8 + j]; st[8 + j] = st[12 + j]; st[12 + j] = t; }
    // CNOT(1,2): q1=1 -> flip q2
    {
        v2f t;
        t = st[4];  st[4]  = st[6];  st[6]  = t;
        t = st[5];  st[5]  = st[7];  st[7]  = t;
        t = st[12]; st[12] = st[14]; st[14] = t;
        t = st[13]; st[13] = st[15]; st[15] = t;
    }
    // CNOT(2,3): q2=1 -> flip q3
    {
        v2f t;
        t = st[2];  st[2]  = st[3];  st[3]  = t;
        t = st[6];  st[6]  = st[7];  st[7]  = t;
        t = st[10]; st[10] = st[11]; st[11] = t;
        t = st[14]; st[14] = st[15]; st[15] = t;
    }
}

__global__ void __launch_bounds__(256, 8) qml_kernel(
        const float* __restrict__ x, const float* __restrict__ g,
        float* __restrict__ out, int batch) {
    int tid = blockIdx.x * blockDim.x + threadIdx.x;
    if (tid >= batch) return;

    float4 xv = reinterpret_cast<const float4*>(x)[tid];
    float c[4], s[4];
    __sincosf(0.5f * xv.x, &s[0], &c[0]);
    __sincosf(0.5f * xv.y, &s[1], &c[1]);
    __sincosf(0.5f * xv.z, &s[2], &c[2]);
    __sincosf(0.5f * xv.w, &s[3], &c[3]);

    // ---- layer 1: product state, per-qubit 2-vectors ----
    // gv[q*4 + {0,1,2,3}] = P,Q,R,S as (re,im) pairs (SGPR pairs after s_load)
    const v2f* __restrict__ gv = reinterpret_cast<const v2f*>(g);
    v2f v[4][2];
    #pragma unroll
    for (int q = 0; q < 4; q++) {
        v[q][0] = pfma(c[q], gv[q * 4 + 0], splat2(s[q]) * gv[q * 4 + 1]);
        v[q][1] = pfma(c[q], gv[q * 4 + 2], splat2(s[q]) * gv[q * 4 + 3]);
    }

    // ---- tensor expansion to 16 amps ----
    v2f t01[4], t23[4], st[16];
    #pragma unroll
    for (int a = 0; a < 2; a++)
        #pragma unroll
        for (int b = 0; b < 2; b++) {
            t01[a * 2 + b] = cmul(v[0][a], v[1][b]);
            t23[a * 2 + b] = cmul(v[2][a], v[3][b]);
        }
    #pragma unroll
    for (int a = 0; a < 4; a++)
        #pragma unroll
        for (int b = 0; b < 4; b++)
            st[a * 4 + b] = cmul(t01[a], t23[b]);

    cnot_chain(st);

    // ---- layer 2: SU(2) = RY(wy)*RX(x) butterflies, all 4 qubits ----
    // al = (ar, ai) = (cb*c, sb*s); be = (br, bi) = (-sb*c, -cb*s)
    // n0' = al*a0 + be*a1
    // n1' = -conj(be)*a0 + conj(al)*a1
    #pragma unroll
    for (int q = 0; q < 4; q++) {
        float cb = g[32 + q * 2 + 0];
        float sb = g[32 + q * 2 + 1];
        float ar  = cb * c[q];
        float ai  = sb * s[q];
        float nbr = sb * c[q];
        float nbi = cb * s[q];
        float br = -nbr, bi = -nbi;
        int bit = 8 >> q;
        #pragma unroll
        for (int n0 = 0; n0 < 16; n0++) {
            if (n0 & bit) continue;
            int n1 = n0 | bit;
            v2f a0 = st[n0], a1 = st[n1];
            v2f a0n = swneg(a0),  a1n = swneg(a1);
            v2f a0c = swconj(a0), a1c = swconj(a1);
            st[n0] = pfma(ar,  a0, pfma(ai,  a0n, pfma(br, a1, splat2(bi) * a1n)));
            st[n1] = pfma(nbr, a0, pfma(nbi, a0c, pfma(ar, a1, splat2(ai) * a1c)));
        }
    }

    cnot_chain(st);

    // ---- probabilities and <Z_i> ----
    float p[16];
    #pragma unroll
    for (int n = 0; n < 16; n++) {
        v2f sq = st[n] * st[n];
        p[n] = sq.x + sq.y;
    }

    float a8[8], z3 = 0.f;
    #pragma unroll
    for (int m = 0; m < 8; m++) { a8[m] = p[2 * m] + p[2 * m + 1]; z3 += p[2 * m] - p[2 * m + 1]; }
    float b4[4], z2 = 0.f;
    #pragma unroll
    for (int k = 0; k < 4; k++) { b4[k] = a8[2 * k] + a8[2 * k + 1]; z2 += a8[2 * k] - a8[2 * k + 1]; }
    float z1 = (b4[0] - b4[1]) + (b4[2] - b4[3]);
    float z0 = (b4[0] + b4[1]) - (b4[2] + b4[3]);

    reinterpret_cast<float4*>(out)[tid] = make_float4(z0, z1, z2, z3);
}

extern "C" void kernel_launch(void* const* d_in, const int* in_sizes, int n_in,
                              void* d_out, int out_size, void* d_ws, size_t ws_size,
                              hipStream_t stream) {
    const float* x = (const float*)d_in[0];      // [B,4]
    const float* w = (const float*)d_in[1];      // [2,4,2]
    float* out = (float*)d_out;                  // [B,4]
    float* g = (float*)d_ws;                     // 40 floats of gate constants
    int batch = in_sizes[0] / 4;

    precompute_gates<<<1, 64, 0, stream>>>(w, g);
    int block = 256;
    int grid = (batch + block - 1) / block;
    qml_kernel<<<grid, block, 0, stream>>>(x, g, out, batch);
}

// Round 8
// 86.318 us; speedup vs baseline: 1.0290x; 1.0290x over previous
//
#include <hip/hip_runtime.h>

// 4-qubit, 2-layer QML circuit, B=1M samples, one thread/sample.
// SINGLE-KERNEL variant of the round-6 champion body: the weight-only gate
// table (40 floats) is computed ONCE PER BLOCK by 8 lanes of wave 0 into LDS
// (~0.1 us one-time), then moved to SGPRs via readfirstlane — preserving the
// round-0/6 property that gate constants occupy zero VGPRs. This deletes the
// serialized precompute_gates graph node and its inter-kernel dependency gap
// (~2-5 us), the last controllable term: fill (~44 us) and the harness reset
// dispatch train are fixed.
//   (Round 1 attacked this wrongly: EVERY THREAD redid 16 transcendental
//    pairs -> +2.8 us. Here it's 8 lanes per block, once.)
//
// Body = round-6 packed form (fill-normalized best, tied with R0/R7):
// float2 ext-vector amplitudes, splat*vec FMA chains (v_pk_fma_f32 with
// op_sel/neg), RZ-drop (layer-2 RZ dead under final CNOT perm + |.|^2),
// layer-2 U = RY(wy)*RX(x) SU(2) butterflies on all 4 qubits, p[16] + tree.
//
// Flat amp index n = q0*8 + q1*4 + q2*2 + q3 (qubit 0 = bit 3).

typedef float v2f __attribute__((ext_vector_type(2)));

__device__ __forceinline__ v2f splat2(float a) { v2f r; r.x = a; r.y = a; return r; }

__device__ __forceinline__ v2f pfma(float a, v2f b, v2f c) {
    return __builtin_elementwise_fma(splat2(a), b, c);
}

// swneg(a) = {-a.y, a.x}   (multiply-by-i pattern; folds to op_sel+neg)
__device__ __forceinline__ v2f swneg(v2f a) { return __builtin_shufflevector(a, -a, 3, 0); }
// swconj(a) = {a.y, -a.x}
__device__ __forceinline__ v2f swconj(v2f a) { return __builtin_shufflevector(a, -a, 1, 2); }

// complex multiply: a*b = splat(a.re)*b + splat(a.im)*{-b.im, b.re}
__device__ __forceinline__ v2f cmul(v2f a, v2f b) {
    return pfma(a.x, b, splat2(a.y) * swneg(b));
}

// wave-uniform LDS value -> SGPR
__device__ __forceinline__ float rf(float v) {
    return __int_as_float(__builtin_amdgcn_readfirstlane(__float_as_int(v)));
}

__device__ __forceinline__ void cnot_chain(v2f st[16]) {
    // CNOT(0,1): q0=1 -> flip q1: swap n=8..11 <-> 12..15
    #pragma unroll
    for (int j = 0; j < 4; j++) { v2f t = st[8 + j]; st[8 + j] = st[12 + j]; st[12 + j] = t; }
    // CNOT(1,2): q1=1 -> flip q2
    {
        v2f t;
        t = st[4];  st[4]  = st[6];  st[6]  = t;
        t = st[5];  st[5]  = st[7];  st[7]  = t;
        t = st[12]; st[12] = st[14]; st[14] = t;
        t = st[13]; st[13] = st[15]; st[15] = t;
    }
    // CNOT(2,3): q2=1 -> flip q3
    {
        v2f t;
        t = st[2];  st[2]  = st[3];  st[3]  = t;
        t = st[6];  st[6]  = st[7];  st[7]  = t;
        t = st[10]; st[10] = st[11]; st[11] = t;
        t = st[14]; st[14] = st[15]; st[15] = t;
    }
}

__global__ void __launch_bounds__(256) qml_kernel(
        const float* __restrict__ x, const float* __restrict__ w,
        float* __restrict__ out, int batch) {
    // ---- per-block gate table: 8 lanes of wave 0 -> LDS (40 floats) ----
    // gs[0..31]: l=0 qubit q: P,Q,R,S as (re,im) pairs
    // gs[32..39]: l=1 qubit q: cos(wy/2), sin(wy/2)   (layer-2 RZ is dead)
    __shared__ float gs[40];
    int lt = threadIdx.x;
    if (lt < 8) {
        int l = lt >> 2, q = lt & 3;
        if (l == 0) {
            float sy, cy, sz, cz;
            __sincosf(0.5f * w[q * 2 + 0], &sy, &cy);
            __sincosf(0.5f * w[q * 2 + 1], &sz, &cz);
            float* o = gs + q * 8;
            // v0 = c*P + s*Q ; v1 = c*R + s*S  (RZ*RY*RX|0>)
            o[0] = cz * cy;  o[1] = -sz * cy;
            o[2] = sz * sy;  o[3] =  cz * sy;
            o[4] = cz * sy;  o[5] =  sz * sy;
            o[6] = sz * cy;  o[7] = -cz * cy;
        } else {
            float sy, cy;
            __sincosf(0.5f * w[8 + q * 2 + 0], &sy, &cy);
            gs[32 + q * 2 + 0] = cy;
            gs[32 + q * 2 + 1] = sy;
        }
    }
    __syncthreads();

    // ---- LDS -> SGPR table (one-time per wave; zero VGPR residency) ----
    float gt[40];
    #pragma unroll
    for (int j = 0; j < 40; j++) gt[j] = rf(gs[j]);

    int tid = blockIdx.x * blockDim.x + threadIdx.x;
    if (tid >= batch) return;

    float4 xv = reinterpret_cast<const float4*>(x)[tid];
    float c[4], s[4];
    __sincosf(0.5f * xv.x, &s[0], &c[0]);
    __sincosf(0.5f * xv.y, &s[1], &c[1]);
    __sincosf(0.5f * xv.z, &s[2], &c[2]);
    __sincosf(0.5f * xv.w, &s[3], &c[3]);

    // ---- layer 1: product state, per-qubit 2-vectors ----
    v2f v[4][2];
    #pragma unroll
    for (int q = 0; q < 4; q++) {
        v2f P; P.x = gt[q * 8 + 0]; P.y = gt[q * 8 + 1];
        v2f Q; Q.x = gt[q * 8 + 2]; Q.y = gt[q * 8 + 3];
        v2f R; R.x = gt[q * 8 + 4]; R.y = gt[q * 8 + 5];
        v2f S; S.x = gt[q * 8 + 6]; S.y = gt[q * 8 + 7];
        v[q][0] = pfma(c[q], P, splat2(s[q]) * Q);
        v[q][1] = pfma(c[q], R, splat2(s[q]) * S);
    }

    // ---- tensor expansion to 16 amps ----
    v2f t01[4], t23[4], st[16];
    #pragma unroll
    for (int a = 0; a < 2; a++)
        #pragma unroll
        for (int b = 0; b < 2; b++) {
            t01[a * 2 + b] = cmul(v[0][a], v[1][b]);
            t23[a * 2 + b] = cmul(v[2][a], v[3][b]);
        }
    #pragma unroll
    for (int a = 0; a < 4; a++)
        #pragma unroll
        for (int b = 0; b < 4; b++)
            st[a * 4 + b] = cmul(t01[a], t23[b]);

    cnot_chain(st);

    // ---- layer 2: SU(2) = RY(wy)*RX(x) butterflies, all 4 qubits ----
    // al = (ar, ai) = (cb*c, sb*s); be = (br, bi) = (-sb*c, -cb*s)
    // n0' = al*a0 + be*a1 ; n1' = -conj(be)*a0 + conj(al)*a1
    #pragma unroll
    for (int q = 0; q < 4; q++) {
        float cb = gt[32 + q * 2 + 0];
        float sb = gt[32 + q * 2 + 1];
        float ar  = cb * c[q];
        float ai  = sb * s[q];
        float nbr = sb * c[q];
        float nbi = cb * s[q];
        float br = -nbr, bi = -nbi;
        int bit = 8 >> q;
        #pragma unroll
        for (int n0 = 0; n0 < 16; n0++) {
            if (n0 & bit) continue;
            int n1 = n0 | bit;
            v2f a0 = st[n0], a1 = st[n1];
            v2f a0n = swneg(a0),  a1n = swneg(a1);
            v2f a0c = swconj(a0), a1c = swconj(a1);
            st[n0] = pfma(ar,  a0, pfma(ai,  a0n, pfma(br, a1, splat2(bi) * a1n)));
            st[n1] = pfma(nbr, a0, pfma(nbi, a0c, pfma(ar, a1, splat2(ai) * a1c)));
        }
    }

    cnot_chain(st);

    // ---- probabilities and <Z_i> ----
    float p[16];
    #pragma unroll
    for (int n = 0; n < 16; n++) {
        v2f sq = st[n] * st[n];
        p[n] = sq.x + sq.y;
    }

    float a8[8], z3 = 0.f;
    #pragma unroll
    for (int m = 0; m < 8; m++) { a8[m] = p[2 * m] + p[2 * m + 1]; z3 += p[2 * m] - p[2 * m + 1]; }
    float b4[4], z2 = 0.f;
    #pragma unroll
    for (int k = 0; k < 4; k++) { b4[k] = a8[2 * k] + a8[2 * k + 1]; z2 += a8[2 * k] - a8[2 * k + 1]; }
    float z1 = (b4[0] - b4[1]) + (b4[2] - b4[3]);
    float z0 = (b4[0] + b4[1]) - (b4[2] + b4[3]);

    reinterpret_cast<float4*>(out)[tid] = make_float4(z0, z1, z2, z3);
}

extern "C" void kernel_launch(void* const* d_in, const int* in_sizes, int n_in,
                              void* d_out, int out_size, void* d_ws, size_t ws_size,
                              hipStream_t stream) {
    const float* x = (const float*)d_in[0];      // [B,4]
    const float* w = (const float*)d_in[1];      // [2,4,2]
    float* out = (float*)d_out;                  // [B,4]
    int batch = in_sizes[0] / 4;

    int block = 256;
    int grid = (batch + block - 1) / block;
    qml_kernel<<<grid, block, 0, stream>>>(x, w, out, batch);
}